// Round 2
// baseline (801.207 us; speedup 1.0000x reference)
//
#include <hip/hip_runtime.h>
#include <hip/hip_bf16.h>

typedef float fx4 __attribute__((ext_vector_type(4)));
typedef short bf8 __attribute__((ext_vector_type(8)));

#define K_TAPS 27
#define CIN 32
#define COUT 32

// round-to-nearest-even f32 -> bf16 (bit pattern as short)
__device__ __forceinline__ short f2bf(float f) {
    unsigned u = __builtin_bit_cast(unsigned, f);
    unsigned r = (u + 0x7fffu + ((u >> 16) & 1u)) >> 16;
    return (short)r;
}

// Pre-pass: convert X (N*32 fp32) to bf16 in workspace. Memory-bound streaming.
__global__ void cvt_kernel(const float* __restrict__ x, short* __restrict__ xb, long n8) {
    long i = (long)blockIdx.x * blockDim.x + threadIdx.x;
    long stride = (long)gridDim.x * blockDim.x;
    for (; i < n8; i += stride) {
        const fx4* p = (const fx4*)(x + i * 8);
        fx4 a = p[0], b = p[1];
        bf8 v;
        v[0] = f2bf(a[0]); v[1] = f2bf(a[1]); v[2] = f2bf(a[2]); v[3] = f2bf(a[3]);
        v[4] = f2bf(b[0]); v[5] = f2bf(b[1]); v[6] = f2bf(b[2]); v[7] = f2bf(b[3]);
        *(bf8*)(xb + i * 8) = v;
    }
}

// Main kernel: one wave computes 16 output rows x 32 couts.
// Block = 1024 threads = 16 waves = 256 rows.
// LDS: W as bf16 [tap][co][ci], ci-chunks XOR-swizzled so B-frag ds_read_b128
// is 2-way (free) instead of 8-way bank-conflicted.
template <bool XBF>
__global__ __launch_bounds__(1024) void conv_kernel(
    const float* __restrict__ x, const short* __restrict__ xb,
    const float* __restrict__ w, const float* __restrict__ bias,
    const int* __restrict__ nb, float* __restrict__ out, int n)
{
    __shared__ short Wl[K_TAPS * COUT * CIN];  // 55296 B

    int tid = threadIdx.x;
    // Stage weights fp32 -> bf16 -> LDS (tiny: 27648 elems, stays L2-hot).
    for (int i = tid; i < K_TAPS * CIN * COUT; i += 1024) {
        int k = i >> 10;
        int ci = (i >> 5) & 31;
        int co = i & 31;
        int swz = (ci >> 3) ^ ((co >> 1) & 3);
        Wl[k * 1024 + co * 32 + swz * 8 + (ci & 7)] = f2bf(w[i]);
    }
    __syncthreads();

    int lane = tid & 63;
    int wave = tid >> 6;
    int r16 = lane & 15;        // A row within tile / output col within half
    int chunk = lane >> 4;      // ci chunk of 8
    long rowBase = (long)blockIdx.x * 256 + wave * 16;
    long grow = rowBase + r16;
    if (grow > (long)n - 1) grow = (long)n - 1;   // tail clamp (loads only)
    size_t nbase = (size_t)grow * K_TAPS;

    int co0 = r16, co1 = r16 + 16;
    const short* bp0 = &Wl[co0 * 32 + ((chunk ^ ((co0 >> 1) & 3)) * 8)];
    const short* bp1 = &Wl[co1 * 32 + ((chunk ^ ((co1 >> 1) & 3)) * 8)];

    fx4 acc0 = {0.f, 0.f, 0.f, 0.f};
    fx4 acc1 = {0.f, 0.f, 0.f, 0.f};

#pragma unroll 3
    for (int k = 0; k < K_TAPS; ++k) {
        int idx = nb[nbase + k];
        bf8 a;
        if constexpr (XBF) {
            a = *(const bf8*)(xb + ((size_t)idx * CIN + chunk * 8));
        } else {
            const float* xr = x + ((size_t)idx * CIN + chunk * 8);
            fx4 xa = *(const fx4*)xr;
            fx4 xc = *(const fx4*)(xr + 4);
            a[0] = f2bf(xa[0]); a[1] = f2bf(xa[1]); a[2] = f2bf(xa[2]); a[3] = f2bf(xa[3]);
            a[4] = f2bf(xc[0]); a[5] = f2bf(xc[1]); a[6] = f2bf(xc[2]); a[7] = f2bf(xc[3]);
        }
        bf8 b0 = *(const bf8*)(bp0 + k * 1024);
        bf8 b1 = *(const bf8*)(bp1 + k * 1024);
        acc0 = __builtin_amdgcn_mfma_f32_16x16x32_bf16(a, b0, acc0, 0, 0, 0);
        acc1 = __builtin_amdgcn_mfma_f32_16x16x32_bf16(a, b1, acc1, 0, 0, 0);
    }

    // D layout (m89-verified): col = lane&15, row = (lane>>4)*4 + q
    float bv0 = bias[co0];
    float bv1 = bias[co1];
#pragma unroll
    for (int q = 0; q < 4; ++q) {
        long orow = rowBase + chunk * 4 + q;
        if (orow < n) {
            float* o = out + orow * COUT;
            o[co0] = acc0[q] + bv0;
            o[co1] = acc1[q] + bv1;
        }
    }
}

extern "C" void kernel_launch(void* const* d_in, const int* in_sizes, int n_in,
                              void* d_out, int out_size, void* d_ws, size_t ws_size,
                              hipStream_t stream) {
    const float* x    = (const float*)d_in[0];   // [N, 32] fp32
    const float* w    = (const float*)d_in[1];   // [27, 32, 32] fp32
    const float* bias = (const float*)d_in[2];   // [32] fp32
    const int*   nb   = (const int*)d_in[3];     // [N, 27] int32
    float* out = (float*)d_out;

    int n = in_sizes[0] / CIN;
    int nblk = (n + 255) / 256;
    size_t xbytes = (size_t)n * CIN * sizeof(short);

    if (ws_size >= xbytes) {
        // Path A: bf16-gather (halves gather traffic; 64 MB stays L3-resident)
        short* xbf = (short*)d_ws;
        long n8 = (long)n * CIN / 8;
        cvt_kernel<<<2048, 256, 0, stream>>>(x, xbf, n8);
        conv_kernel<true><<<nblk, 1024, 0, stream>>>(x, xbf, w, bias, nb, out, n);
    } else {
        // Path C: fp32 gather, convert in-register (no workspace dependency)
        conv_kernel<false><<<nblk, 1024, 0, stream>>>(x, nullptr, w, bias, nb, out, n);
    }
}

// Round 3
// 754.251 us; speedup vs baseline: 1.0623x; 1.0623x over previous
//
#include <hip/hip_runtime.h>
#include <hip/hip_bf16.h>

typedef float fx4 __attribute__((ext_vector_type(4)));
typedef short bf8 __attribute__((ext_vector_type(8)));

#define K_TAPS 27
#define CIN 32
#define COUT 32
#define PF_DEPTH 9

// round-to-nearest-even f32 -> bf16 (bit pattern as short)
__device__ __forceinline__ short f2bf(float f) {
    unsigned u = __builtin_bit_cast(unsigned, f);
    unsigned r = (u + 0x7fffu + ((u >> 16) & 1u)) >> 16;
    return (short)r;
}

// Pre-pass: convert X (N*32 fp32) to bf16 in workspace. Memory-bound streaming.
__global__ void cvt_kernel(const float* __restrict__ x, short* __restrict__ xb, long n8) {
    long i = (long)blockIdx.x * blockDim.x + threadIdx.x;
    long stride = (long)gridDim.x * blockDim.x;
    for (; i < n8; i += stride) {
        const fx4* p = (const fx4*)(x + i * 8);
        fx4 a = p[0], b = p[1];
        bf8 v;
        v[0] = f2bf(a[0]); v[1] = f2bf(a[1]); v[2] = f2bf(a[2]); v[3] = f2bf(a[3]);
        v[4] = f2bf(b[0]); v[5] = f2bf(b[1]); v[6] = f2bf(b[2]); v[7] = f2bf(b[3]);
        *(bf8*)(xb + i * 8) = v;
    }
}

// Main kernel: one wave computes 16 output rows x 32 couts via mfma_16x16x32_bf16.
// Block = 1024 threads = 16 waves = 256 rows.
// MLP restructure (R3): preload all 27 neighbor idx per lane (breaks the
// idx->gather dependent chain), then explicit depth-9 software pipeline on the
// gathers (all indices compile-time under full unroll -> registers, rule #20).
template <bool XBF>
__global__ __launch_bounds__(1024, 4) void conv_kernel(
    const float* __restrict__ x, const short* __restrict__ xb,
    const float* __restrict__ w, const float* __restrict__ bias,
    const int* __restrict__ nb, float* __restrict__ out, int n)
{
    __shared__ short Wl[K_TAPS * COUT * CIN];  // 55296 B

    int tid = threadIdx.x;
    // Stage weights fp32 -> bf16 -> LDS, ci-chunks XOR-swizzled so the B-frag
    // ds_read_b128 is 2-way (free) instead of 8-way bank-conflicted.
    for (int i = tid; i < K_TAPS * CIN * COUT; i += 1024) {
        int k = i >> 10;
        int ci = (i >> 5) & 31;
        int co = i & 31;
        int swz = (ci >> 3) ^ ((co >> 1) & 3);
        Wl[k * 1024 + co * 32 + swz * 8 + (ci & 7)] = f2bf(w[i]);
    }
    __syncthreads();

    int lane = tid & 63;
    int wave = tid >> 6;
    int r16 = lane & 15;        // A row within tile / output col within half
    int chunk = lane >> 4;      // ci chunk of 8
    long rowBase = (long)blockIdx.x * 256 + wave * 16;
    long grow = rowBase + r16;
    if (grow > (long)n - 1) grow = (long)n - 1;   // tail clamp (loads only)

    int co0 = r16, co1 = r16 + 16;
    const short* bp0 = &Wl[co0 * 32 + ((chunk ^ ((co0 >> 1) & 3)) * 8)];
    const short* bp1 = &Wl[co1 * 32 + ((chunk ^ ((co1 >> 1) & 3)) * 8)];

    fx4 acc0 = {0.f, 0.f, 0.f, 0.f};
    fx4 acc1 = {0.f, 0.f, 0.f, 0.f};

    if constexpr (XBF) {
        const int* nbp = nb + (size_t)grow * K_TAPS;
        int idxs[K_TAPS];
#pragma unroll
        for (int k = 0; k < K_TAPS; ++k) idxs[k] = nbp[k];  // 27 independent loads

        bf8 abuf[PF_DEPTH];
#pragma unroll
        for (int k = 0; k < PF_DEPTH; ++k)
            abuf[k] = *(const bf8*)(xb + ((size_t)idxs[k] * CIN + chunk * 8));

#pragma unroll
        for (int k = 0; k < K_TAPS; ++k) {
            bf8 a = abuf[k % PF_DEPTH];
            if (k + PF_DEPTH < K_TAPS)   // compile-time per unrolled iteration
                abuf[k % PF_DEPTH] =
                    *(const bf8*)(xb + ((size_t)idxs[k + PF_DEPTH] * CIN + chunk * 8));
            bf8 b0 = *(const bf8*)(bp0 + k * 1024);
            bf8 b1 = *(const bf8*)(bp1 + k * 1024);
            acc0 = __builtin_amdgcn_mfma_f32_16x16x32_bf16(a, b0, acc0, 0, 0, 0);
            acc1 = __builtin_amdgcn_mfma_f32_16x16x32_bf16(a, b1, acc1, 0, 0, 0);
        }
    } else {
        // Fallback: fp32 gather, convert in-register (no workspace dependency).
        size_t nbase = (size_t)grow * K_TAPS;
#pragma unroll 3
        for (int k = 0; k < K_TAPS; ++k) {
            int idx = nb[nbase + k];
            const float* xr = x + ((size_t)idx * CIN + chunk * 8);
            fx4 xa = *(const fx4*)xr;
            fx4 xc = *(const fx4*)(xr + 4);
            bf8 a;
            a[0] = f2bf(xa[0]); a[1] = f2bf(xa[1]); a[2] = f2bf(xa[2]); a[3] = f2bf(xa[3]);
            a[4] = f2bf(xc[0]); a[5] = f2bf(xc[1]); a[6] = f2bf(xc[2]); a[7] = f2bf(xc[3]);
            bf8 b0 = *(const bf8*)(bp0 + k * 1024);
            bf8 b1 = *(const bf8*)(bp1 + k * 1024);
            acc0 = __builtin_amdgcn_mfma_f32_16x16x32_bf16(a, b0, acc0, 0, 0, 0);
            acc1 = __builtin_amdgcn_mfma_f32_16x16x32_bf16(a, b1, acc1, 0, 0, 0);
        }
    }

    // D layout (m89-verified): col = lane&15, row = (lane>>4)*4 + q
    // Output is write-once, never re-read -> nontemporal keeps L2 clean for gathers.
    float bv0 = bias[co0];
    float bv1 = bias[co1];
#pragma unroll
    for (int q = 0; q < 4; ++q) {
        long orow = rowBase + chunk * 4 + q;
        if (orow < n) {
            float* o = out + orow * COUT;
            __builtin_nontemporal_store(acc0[q] + bv0, o + co0);
            __builtin_nontemporal_store(acc1[q] + bv1, o + co1);
        }
    }
}

extern "C" void kernel_launch(void* const* d_in, const int* in_sizes, int n_in,
                              void* d_out, int out_size, void* d_ws, size_t ws_size,
                              hipStream_t stream) {
    const float* x    = (const float*)d_in[0];   // [N, 32] fp32
    const float* w    = (const float*)d_in[1];   // [27, 32, 32] fp32
    const float* bias = (const float*)d_in[2];   // [32] fp32
    const int*   nb   = (const int*)d_in[3];     // [N, 27] int32
    float* out = (float*)d_out;

    int n = in_sizes[0] / CIN;
    int nblk = (n + 255) / 256;
    size_t xbytes = (size_t)n * CIN * sizeof(short);

    if (ws_size >= xbytes) {
        // Path A: bf16-gather (halves gather traffic; 64 MB X stays cache-resident)
        short* xbf = (short*)d_ws;
        long n8 = (long)n * CIN / 8;
        cvt_kernel<<<4096, 256, 0, stream>>>(x, xbf, n8);
        conv_kernel<true><<<nblk, 1024, 0, stream>>>(x, xbf, w, bias, nb, out, n);
    } else {
        // Path C: fp32 gather, convert in-register (no workspace dependency)
        conv_kernel<false><<<nblk, 1024, 0, stream>>>(x, nullptr, w, bias, nb, out, n);
    }
}